// Round 2
// baseline (150.262 us; speedup 1.0000x reference)
//
#include <hip/hip_runtime.h>
#include <hip/hip_bf16.h>
#include <math.h>

#define NN 4096
#define DD 1024
#define NCLS 128
#define TAU 0.5f
#define EPSV 1e-8f

typedef __bf16 bf16;
typedef __bf16 bf16x8 __attribute__((ext_vector_type(8)));
typedef __bf16 bf16x4 __attribute__((ext_vector_type(4)));
typedef float f32x4 __attribute__((ext_vector_type(4)));

__device__ __forceinline__ void gl2lds16(const void* g, void* l) {
    __builtin_amdgcn_global_load_lds(
        (const __attribute__((address_space(1))) void*)g,
        (__attribute__((address_space(3))) void*)l,
        16, 0, 0);
}

// K1: per-row L2 norm, write normalized bf16 copy. One wave per row.
__global__ __launch_bounds__(256) void k_norm_cast(const float* __restrict__ X,
                                                   bf16* __restrict__ Xn,
                                                   float* __restrict__ norms) {
    int w = threadIdx.x >> 6, lane = threadIdx.x & 63;
    int row = blockIdx.x * 4 + w;
    const float* xr = X + (size_t)row * DD;
    float4 v[4];
    float ss = 0.f;
#pragma unroll
    for (int c = 0; c < 4; ++c) {
        v[c] = *(const float4*)(xr + c * 256 + lane * 4);
        ss += v[c].x * v[c].x + v[c].y * v[c].y + v[c].z * v[c].z + v[c].w * v[c].w;
    }
#pragma unroll
    for (int m = 1; m < 64; m <<= 1) ss += __shfl_xor(ss, m, 64);
    float nrm = sqrtf(ss);
    if (lane == 0) norms[row] = nrm;
    float rn = 1.f / fmaxf(nrm, EPSV);
#pragma unroll
    for (int c = 0; c < 4; ++c) {
        bf16x4 o;
        o.x = (bf16)(v[c].x * rn);
        o.y = (bf16)(v[c].y * rn);
        o.z = (bf16)(v[c].z * rn);
        o.w = (bf16)(v[c].w * rn);
        *(bf16x4*)(Xn + (size_t)row * DD + c * 256 + lane * 4) = o;
    }
}

// K2: class counts + min index per class
__global__ __launch_bounds__(256) void k_classes1(const int* __restrict__ y,
                                                  int* __restrict__ cnt,
                                                  int* __restrict__ mn1) {
    int i = blockIdx.x * 256 + threadIdx.x;
    int c = y[i];
    atomicAdd(&cnt[c], 1);
    atomicMin(&mn1[c], i);
}

// K3: second-min index per class
__global__ __launch_bounds__(256) void k_classes2(const int* __restrict__ y,
                                                  const int* __restrict__ mn1,
                                                  int* __restrict__ mn2) {
    int i = blockIdx.x * 256 + threadIdx.x;
    int c = y[i];
    if (mn1[c] != i) atomicMin(&mn2[c], i);
}

// K4: pos_val[i] = (cos(x_i, x_firstpos)+1)*0.5*TAU, fp32 exact. One wave per row.
__global__ __launch_bounds__(256) void k_posval(const float* __restrict__ X,
                                                const float* __restrict__ norms,
                                                const int* __restrict__ y,
                                                const int* __restrict__ cnt,
                                                const int* __restrict__ mn1,
                                                const int* __restrict__ mn2,
                                                float* __restrict__ posv) {
    int w = threadIdx.x >> 6, lane = threadIdx.x & 63;
    int i = blockIdx.x * 4 + w;
    int c = y[i];
    float pv = 0.f;
    if (cnt[c] >= 2) {
        int fp = (mn1[c] == i) ? mn2[c] : mn1[c];
        const float* xi = X + (size_t)i * DD;
        const float* xf = X + (size_t)fp * DD;
        float dot = 0.f;
#pragma unroll
        for (int cc = 0; cc < 4; ++cc) {
            float4 a = *(const float4*)(xi + cc * 256 + lane * 4);
            float4 b = *(const float4*)(xf + cc * 256 + lane * 4);
            dot += a.x * b.x + a.y * b.y + a.z * b.z + a.w * b.w;
        }
#pragma unroll
        for (int m = 1; m < 64; m <<= 1) dot += __shfl_xor(dot, m, 64);
        float ni = fmaxf(norms[i], EPSV), nf = fmaxf(norms[fp], EPSV);
        pv = (dot / (ni * nf) + 1.f) * (0.5f * TAU);
    }
    if (lane == 0) posv[i] = pv;
}

// K5: 128x128-tile bf16 MFMA gram kernel with fused exp/mask epilogue.
// rowsum[i] += sum_j in tile-cols, y_j != y_i of exp((cos_ij+1)*0.25)
__global__ __launch_bounds__(256) void k_gemm(const bf16* __restrict__ Xn,
                                              const int* __restrict__ y,
                                              float* __restrict__ rowsum) {
    __shared__ __align__(16) bf16 As[128 * 32];
    __shared__ __align__(16) bf16 Bs[128 * 32];
    __shared__ int yA[128], yB[128];

    const int tid = threadIdx.x;
    const int rowA0 = blockIdx.y * 128;
    const int rowB0 = blockIdx.x * 128;
    if (tid < 128) yA[tid] = y[rowA0 + tid];
    else           yB[tid - 128] = y[rowB0 + tid - 128];

    const int lane = tid & 63;
    const int w = tid >> 6;
    const int wm = w & 1, wn = w >> 1;     // 2x2 waves -> each wave 64x64
    const int lr = lane >> 4, lc = lane & 15;

    f32x4 acc[4][4];
#pragma unroll
    for (int i = 0; i < 4; ++i)
#pragma unroll
        for (int j = 0; j < 4; ++j) acc[i][j] = (f32x4){0.f, 0.f, 0.f, 0.f};

    const int r = tid >> 2;  // 0..63: row within half-tile
    const int g = tid & 3;   // 0..3 : 8-elt k-group
    const bf16* gA0 = Xn + (size_t)(rowA0 + r) * DD + g * 8;
    const bf16* gA1 = gA0 + (size_t)64 * DD;
    const bf16* gB0 = Xn + (size_t)(rowB0 + r) * DD + g * 8;
    const bf16* gB1 = gB0 + (size_t)64 * DD;
    bf16* lA0 = As + tid * 8;
    bf16* lA1 = As + 64 * 32 + tid * 8;
    bf16* lB0 = Bs + tid * 8;
    bf16* lB1 = Bs + 64 * 32 + tid * 8;

    for (int k0 = 0; k0 < DD; k0 += 32) {
        __syncthreads();
        gl2lds16(gA0 + k0, lA0);
        gl2lds16(gA1 + k0, lA1);
        gl2lds16(gB0 + k0, lB0);
        gl2lds16(gB1 + k0, lB1);
        __syncthreads();

        bf16x8 af[4], bfr[4];
#pragma unroll
        for (int mt = 0; mt < 4; ++mt)
            af[mt] = *(const bf16x8*)(As + (wm * 64 + mt * 16 + lc) * 32 + lr * 8);
#pragma unroll
        for (int nt = 0; nt < 4; ++nt)
            bfr[nt] = *(const bf16x8*)(Bs + (wn * 64 + nt * 16 + lc) * 32 + lr * 8);
#pragma unroll
        for (int mt = 0; mt < 4; ++mt)
#pragma unroll
            for (int nt = 0; nt < 4; ++nt)
                acc[mt][nt] = __builtin_amdgcn_mfma_f32_16x16x32_bf16(
                    af[mt], bfr[nt], acc[mt][nt], 0, 0, 0);
    }

    // Epilogue: S=(c+1)*0.25; mask same-class (incl. diagonal); per-row sum of exp.
    int ycol[4];
#pragma unroll
    for (int nt = 0; nt < 4; ++nt) ycol[nt] = yB[wn * 64 + nt * 16 + lc];
#pragma unroll
    for (int mt = 0; mt < 4; ++mt) {
#pragma unroll
        for (int rr = 0; rr < 4; ++rr) {
            int rloc = wm * 64 + mt * 16 + lr * 4 + rr;  // C row = (lane>>4)*4+reg
            int yrow = yA[rloc];
            float s = 0.f;
#pragma unroll
            for (int nt = 0; nt < 4; ++nt) {
                float Sv = (acc[mt][nt][rr] + 1.f) * (0.5f * TAU);
                if (ycol[nt] != yrow) s += __expf(Sv);
            }
            // reduce over the 16 lanes holding this row's 16 cols (xor within width 16)
            s += __shfl_xor(s, 1, 16);
            s += __shfl_xor(s, 2, 16);
            s += __shfl_xor(s, 4, 16);
            s += __shfl_xor(s, 8, 16);
            if (lc == 0) atomicAdd(&rowsum[rowA0 + rloc], s);
        }
    }
}

// K6: lse_i = log(rowsum_i + exp(pv_i) + (N-2+cnt)); loss = mean(lse - pv)
__global__ __launch_bounds__(256) void k_finalize(const float* __restrict__ rowsum,
                                                  const float* __restrict__ posv,
                                                  const int* __restrict__ y,
                                                  const int* __restrict__ cnt,
                                                  float* __restrict__ out) {
    int i = blockIdx.x * 256 + threadIdx.x;
    float pv = posv[i];
    float tot = rowsum[i] + __expf(pv) + (float)(NN - 2 + cnt[y[i]]);
    float contrib = logf(tot) - pv;
#pragma unroll
    for (int m = 1; m < 64; m <<= 1) contrib += __shfl_xor(contrib, m, 64);
    __shared__ float wsum[4];
    int w = threadIdx.x >> 6, lane = threadIdx.x & 63;
    if (lane == 0) wsum[w] = contrib;
    __syncthreads();
    if (threadIdx.x == 0)
        atomicAdd(out, (wsum[0] + wsum[1] + wsum[2] + wsum[3]) / (float)NN);
}

extern "C" void kernel_launch(void* const* d_in, const int* in_sizes, int n_in,
                              void* d_out, int out_size, void* d_ws, size_t ws_size,
                              hipStream_t stream) {
    const float* X = (const float*)d_in[0];
    const int* y = (const int*)d_in[1];
    float* out = (float*)d_out;

    char* ws = (char*)d_ws;
    bf16* Xn     = (bf16*)ws;                                  // 8 MB
    float* norms = (float*)(ws + 8 * 1024 * 1024);             // 16 KB
    float* rsum  = (float*)(ws + 8 * 1024 * 1024 + 16 * 1024); // 16 KB
    float* posv  = (float*)(ws + 8 * 1024 * 1024 + 32 * 1024); // 16 KB
    int* cnt     = (int*)(ws + 8 * 1024 * 1024 + 48 * 1024);   // 512 B
    int* mn1     = (int*)(ws + 8 * 1024 * 1024 + 48 * 1024 + 512);
    int* mn2     = (int*)(ws + 8 * 1024 * 1024 + 48 * 1024 + 1024);

    (void)hipMemsetAsync(rsum, 0, NN * sizeof(float), stream);
    (void)hipMemsetAsync(cnt, 0, NCLS * sizeof(int), stream);
    (void)hipMemsetAsync(mn1, 0x7f, 2 * NCLS * sizeof(int), stream);  // mn1+mn2 -> huge
    (void)hipMemsetAsync(out, 0, sizeof(float), stream);

    k_norm_cast<<<dim3(NN / 4), 256, 0, stream>>>(X, Xn, norms);
    k_classes1<<<dim3(NN / 256), 256, 0, stream>>>(y, cnt, mn1);
    k_classes2<<<dim3(NN / 256), 256, 0, stream>>>(y, mn1, mn2);
    k_posval<<<dim3(NN / 4), 256, 0, stream>>>(X, norms, y, cnt, mn1, mn2, posv);
    k_gemm<<<dim3(32, 32), 256, 0, stream>>>(Xn, y, rsum);
    k_finalize<<<dim3(NN / 256), 256, 0, stream>>>(rsum, posv, y, cnt, out);
}

// Round 3
// 106.518 us; speedup vs baseline: 1.4107x; 1.4107x over previous
//
#include <hip/hip_runtime.h>
#include <hip/hip_bf16.h>
#include <math.h>

#define NN 4096
#define DD 1024
#define NCLS 128
#define TAU 0.5f
#define EPSV 1e-8f

typedef __bf16 bf16;
typedef __bf16 bf16x8 __attribute__((ext_vector_type(8)));
typedef __bf16 bf16x4 __attribute__((ext_vector_type(4)));
typedef float f32x4 __attribute__((ext_vector_type(4)));

__device__ __forceinline__ void gl2lds16(const void* g, void* l) {
    __builtin_amdgcn_global_load_lds(
        (const __attribute__((address_space(1))) void*)g,
        (__attribute__((address_space(3))) void*)l,
        16, 0, 0);
}

// K1: per-row L2 norm -> normalized bf16 copy; also zero rowsum. One wave per row.
__global__ __launch_bounds__(256) void k_norm_cast(const float* __restrict__ X,
                                                   bf16* __restrict__ Xn,
                                                   float* __restrict__ rsum) {
    int w = threadIdx.x >> 6, lane = threadIdx.x & 63;
    int row = blockIdx.x * 4 + w;
    const float* xr = X + (size_t)row * DD;
    float4 v[4];
    float ss = 0.f;
#pragma unroll
    for (int c = 0; c < 4; ++c) {
        v[c] = *(const float4*)(xr + c * 256 + lane * 4);
        ss += v[c].x * v[c].x + v[c].y * v[c].y + v[c].z * v[c].z + v[c].w * v[c].w;
    }
#pragma unroll
    for (int m = 1; m < 64; m <<= 1) ss += __shfl_xor(ss, m, 64);
    float rn = 1.f / fmaxf(sqrtf(ss), EPSV);
    if (lane == 0) rsum[row] = 0.f;
#pragma unroll
    for (int c = 0; c < 4; ++c) {
        bf16x4 o;
        o.x = (bf16)(v[c].x * rn);
        o.y = (bf16)(v[c].y * rn);
        o.z = (bf16)(v[c].z * rn);
        o.w = (bf16)(v[c].w * rn);
        *(bf16x4*)(Xn + (size_t)row * DD + c * 256 + lane * 4) = o;
    }
}

// K2: fused class stats in one workgroup (self-initializing, LDS atomics):
// cnt[c], mn1[c]=min index, mn2[c]=second-min index.
__global__ __launch_bounds__(1024) void k_classes(const int* __restrict__ y,
                                                  int* __restrict__ cnt,
                                                  int* __restrict__ mn1,
                                                  int* __restrict__ mn2) {
    __shared__ int sc[NCLS], s1[NCLS], s2[NCLS];
    int t = threadIdx.x;
    if (t < NCLS) { sc[t] = 0; s1[t] = 0x7fffffff; s2[t] = 0x7fffffff; }
    __syncthreads();
    int yv[4];
#pragma unroll
    for (int k = 0; k < 4; ++k) {
        int i = t + k * 1024;
        yv[k] = y[i];
        atomicAdd(&sc[yv[k]], 1);
        atomicMin(&s1[yv[k]], i);
    }
    __syncthreads();
#pragma unroll
    for (int k = 0; k < 4; ++k) {
        int i = t + k * 1024;
        if (s1[yv[k]] != i) atomicMin(&s2[yv[k]], i);
    }
    __syncthreads();
    if (t < NCLS) { cnt[t] = sc[t]; mn1[t] = s1[t]; mn2[t] = s2[t]; }
}

// K3: pos_val[i] = (dot(Xn_i, Xn_firstpos)+1)*0.5*TAU (rows are unit vectors).
__global__ __launch_bounds__(256) void k_posval(const bf16* __restrict__ Xn,
                                                const int* __restrict__ y,
                                                const int* __restrict__ cnt,
                                                const int* __restrict__ mn1,
                                                const int* __restrict__ mn2,
                                                float* __restrict__ posv) {
    int w = threadIdx.x >> 6, lane = threadIdx.x & 63;
    int i = blockIdx.x * 4 + w;
    int c = y[i];
    float pv = 0.f;
    if (cnt[c] >= 2) {
        int fp = (mn1[c] == i) ? mn2[c] : mn1[c];
        const bf16* xi = Xn + (size_t)i * DD;
        const bf16* xf = Xn + (size_t)fp * DD;
        float dot = 0.f;
#pragma unroll
        for (int cc = 0; cc < 2; ++cc) {
            bf16x8 a = *(const bf16x8*)(xi + cc * 512 + lane * 8);
            bf16x8 b = *(const bf16x8*)(xf + cc * 512 + lane * 8);
#pragma unroll
            for (int e = 0; e < 8; ++e) dot += (float)a[e] * (float)b[e];
        }
#pragma unroll
        for (int m = 1; m < 64; m <<= 1) dot += __shfl_xor(dot, m, 64);
        pv = (dot + 1.f) * (0.5f * TAU);
    }
    if (lane == 0) posv[i] = pv;
}

// K4: upper-triangle 128x128-tile bf16 MFMA gram with fused exp/mask epilogue.
// Off-diagonal tiles contribute to rowsum via row-reduce AND col-reduce (symmetry).
__global__ __launch_bounds__(256) void k_gemm(const bf16* __restrict__ Xn,
                                              const int* __restrict__ y,
                                              float* __restrict__ rowsum) {
    __shared__ __align__(16) bf16 As[128 * 32];
    __shared__ __align__(16) bf16 Bs[128 * 32];
    __shared__ int yA[128], yB[128];

    // decode linear block id -> (bi, bj), bi <= bj
    int id = blockIdx.x;
    float ff = sqrtf((float)(8 * id + 1));
    int bj = (int)((ff - 1.f) * 0.5f);
    if (bj * (bj + 1) / 2 > id) bj--;
    if ((bj + 1) * (bj + 2) / 2 <= id) bj++;
    int bi = id - bj * (bj + 1) / 2;
    const int rowA0 = bi * 128;
    const int rowB0 = bj * 128;
    const bool diag = (bi == bj);

    const int tid = threadIdx.x;
    if (tid < 128) yA[tid] = y[rowA0 + tid];
    else           yB[tid - 128] = y[rowB0 + tid - 128];

    const int lane = tid & 63;
    const int w = tid >> 6;
    const int wm = w & 1, wn = w >> 1;     // 2x2 waves -> each wave 64x64
    const int lr = lane >> 4, lc = lane & 15;

    f32x4 acc[4][4];
#pragma unroll
    for (int i = 0; i < 4; ++i)
#pragma unroll
        for (int j = 0; j < 4; ++j) acc[i][j] = (f32x4){0.f, 0.f, 0.f, 0.f};

    // staging with k-slot XOR swizzle: slot g of row r holds k-group g^((r>>1)&3)
    const int r = tid >> 2;
    const int g = tid & 3;
    const int kg = g ^ ((r >> 1) & 3);
    const bf16* gA0 = Xn + (size_t)(rowA0 + r) * DD + kg * 8;
    const bf16* gA1 = gA0 + (size_t)64 * DD;
    const bf16* gB0 = Xn + (size_t)(rowB0 + r) * DD + kg * 8;
    const bf16* gB1 = gB0 + (size_t)64 * DD;
    bf16* lA0 = As + tid * 8;
    bf16* lA1 = As + 64 * 32 + tid * 8;
    bf16* lB0 = Bs + tid * 8;
    bf16* lB1 = Bs + 64 * 32 + tid * 8;

    const int sw = (lc >> 1) & 3;   // read-side swizzle (row = ...16*mt + lc)

    for (int k0 = 0; k0 < DD; k0 += 32) {
        __syncthreads();
        gl2lds16(gA0 + k0, lA0);
        gl2lds16(gA1 + k0, lA1);
        gl2lds16(gB0 + k0, lB0);
        gl2lds16(gB1 + k0, lB1);
        __syncthreads();

        bf16x8 af[4], bfr[4];
#pragma unroll
        for (int mt = 0; mt < 4; ++mt)
            af[mt] = *(const bf16x8*)(As + (wm * 64 + mt * 16 + lc) * 32 + ((lr ^ sw) * 8));
#pragma unroll
        for (int nt = 0; nt < 4; ++nt)
            bfr[nt] = *(const bf16x8*)(Bs + (wn * 64 + nt * 16 + lc) * 32 + ((lr ^ sw) * 8));
#pragma unroll
        for (int mt = 0; mt < 4; ++mt)
#pragma unroll
            for (int nt = 0; nt < 4; ++nt)
                acc[mt][nt] = __builtin_amdgcn_mfma_f32_16x16x32_bf16(
                    af[mt], bfr[nt], acc[mt][nt], 0, 0, 0);
    }

    // Epilogue: S=(c+1)*0.25; mask same-class (incl. diagonal); row+col exp-sums.
    int ycol[4];
#pragma unroll
    for (int nt = 0; nt < 4; ++nt) ycol[nt] = yB[wn * 64 + nt * 16 + lc];
    float colacc[4] = {0.f, 0.f, 0.f, 0.f};
#pragma unroll
    for (int mt = 0; mt < 4; ++mt) {
#pragma unroll
        for (int rr = 0; rr < 4; ++rr) {
            int rloc = wm * 64 + mt * 16 + lr * 4 + rr;  // C row = (lane>>4)*4+reg
            int yrow = yA[rloc];
            float s = 0.f;
#pragma unroll
            for (int nt = 0; nt < 4; ++nt) {
                float Sv = (acc[mt][nt][rr] + 1.f) * (0.5f * TAU);
                float e = (ycol[nt] != yrow) ? __expf(Sv) : 0.f;
                s += e;
                colacc[nt] += e;
            }
            s += __shfl_xor(s, 1, 16);
            s += __shfl_xor(s, 2, 16);
            s += __shfl_xor(s, 4, 16);
            s += __shfl_xor(s, 8, 16);
            if (lc == 0) atomicAdd(&rowsum[rowA0 + rloc], s);
        }
    }
    if (!diag) {
#pragma unroll
        for (int nt = 0; nt < 4; ++nt) {
            float cs = colacc[nt];
            cs += __shfl_xor(cs, 16, 64);
            cs += __shfl_xor(cs, 32, 64);
            if (lane < 16) atomicAdd(&rowsum[rowB0 + wn * 64 + nt * 16 + lane], cs);
        }
    }
}

// K5: single block; lse_i = log(rowsum_i + exp(pv_i) + (N-2+cnt)); out = mean(lse - pv)
__global__ __launch_bounds__(1024) void k_finalize(const float* __restrict__ rowsum,
                                                   const float* __restrict__ posv,
                                                   const int* __restrict__ y,
                                                   const int* __restrict__ cnt,
                                                   float* __restrict__ out) {
    int t = threadIdx.x;
    float acc = 0.f;
#pragma unroll
    for (int k = 0; k < 4; ++k) {
        int i = t + k * 1024;
        float pv = posv[i];
        float tot = rowsum[i] + __expf(pv) + (float)(NN - 2 + cnt[y[i]]);
        acc += logf(tot) - pv;
    }
#pragma unroll
    for (int m = 1; m < 64; m <<= 1) acc += __shfl_xor(acc, m, 64);
    __shared__ float wsum[16];
    int w = t >> 6, lane = t & 63;
    if (lane == 0) wsum[w] = acc;
    __syncthreads();
    if (t == 0) {
        float s = 0.f;
#pragma unroll
        for (int q = 0; q < 16; ++q) s += wsum[q];
        *out = s / (float)NN;
    }
}

extern "C" void kernel_launch(void* const* d_in, const int* in_sizes, int n_in,
                              void* d_out, int out_size, void* d_ws, size_t ws_size,
                              hipStream_t stream) {
    const float* X = (const float*)d_in[0];
    const int* y = (const int*)d_in[1];
    float* out = (float*)d_out;

    char* ws = (char*)d_ws;
    bf16* Xn     = (bf16*)ws;                                  // 8 MB
    float* rsum  = (float*)(ws + 8 * 1024 * 1024);             // 16 KB
    float* posv  = (float*)(ws + 8 * 1024 * 1024 + 16 * 1024); // 16 KB
    int* cnt     = (int*)(ws + 8 * 1024 * 1024 + 32 * 1024);
    int* mn1     = (int*)(ws + 8 * 1024 * 1024 + 32 * 1024 + 512);
    int* mn2     = (int*)(ws + 8 * 1024 * 1024 + 32 * 1024 + 1024);

    k_norm_cast<<<dim3(NN / 4), 256, 0, stream>>>(X, Xn, rsum);
    k_classes<<<dim3(1), 1024, 0, stream>>>(y, cnt, mn1, mn2);
    k_posval<<<dim3(NN / 4), 256, 0, stream>>>(Xn, y, cnt, mn1, mn2, posv);
    k_gemm<<<dim3(528), 256, 0, stream>>>(Xn, y, rsum);
    k_finalize<<<dim3(1), 1024, 0, stream>>>(rsum, posv, y, cnt, out);
}